// Round 12
// baseline (401.880 us; speedup 1.0000x reference)
//
#include <hip/hip_runtime.h>
#include <hip/hip_fp16.h>

#define NNODES    500000
#define SBSH      10            // super-bucket = dst >> 10
#define NSB       512           // super-bucket count (covers 524288 >= N)
#define SBN       1024          // nodes per super-bucket
#define CAP       17024         // staged region words (mean 15625, +11 sigma), mult of 16
#define CHUNK     4096          // edges per scatter block
#define NAGG1     977           // ceil(N/512) — agg1 grid, 2 nodes/thread
#define NBIN      8192          // passB bins: dst_low10 * 8 + src_high3
#define PBT       512           // passB threads per block

// bin key: group rows by dst, order within row by src-chunk (2 MB y2h windows)
#define BIN(p) ((int)(((p) >> 19) * 8u + (((p) & 0x7FFFFu) >> 16)))

// ---------------- pass 1: coarse scatter, LDS counting-sort + coalesced flush ----------------
__global__ __launch_bounds__(256) void scatter_kernel(const int* __restrict__ src,
                                                      const int* __restrict__ dst,
                                                      int* __restrict__ gcursor,
                                                      unsigned int* __restrict__ staged, int E) {
    __shared__ int cnt[NSB];                 // histogram -> start[] after scan
    __shared__ int addb[NSB];                // global seg base -> addbase = gbase - start
    __shared__ int lcur[NSB];                // LDS sort cursors
    __shared__ int tsum[256];
    __shared__ unsigned int sorted[CHUNK];   // 16 KB payloads, bucket-ordered
    __shared__ unsigned short sbuck[CHUNK];  // 8 KB bucket id per slot

    const int t = threadIdx.x;
    for (int i = t; i < NSB; i += 256) cnt[i] = 0;
    __syncthreads();

    const int lo = blockIdx.x * CHUNK;
    const int hi = min(E, lo + CHUNK);
    const int len = hi - lo;
    const int len4 = lo + (len & ~3);

    // pass 1: bucket histogram
    for (int i = lo + 4 * t; i < len4; i += 1024) {
        uint4 d4 = *(const uint4*)(dst + i);
        atomicAdd(&cnt[d4.x >> SBSH], 1);
        atomicAdd(&cnt[d4.y >> SBSH], 1);
        atomicAdd(&cnt[d4.z >> SBSH], 1);
        atomicAdd(&cnt[d4.w >> SBSH], 1);
    }
    for (int i = len4 + t; i < hi; i += 256)
        atomicAdd(&cnt[((unsigned)dst[i]) >> SBSH], 1);
    __syncthreads();

    // reserve global segments (one atomic per nonzero bucket per block)
    for (int b = t; b < NSB; b += 256) {
        int c = cnt[b];
        addb[b] = c ? atomicAdd(&gcursor[b], c) : 0;
    }
    __syncthreads();

    // exclusive scan of 512 counts (2 per thread + block scan over partials)
    int c0 = cnt[2 * t], c1 = cnt[2 * t + 1];
    int s01 = c0 + c1;
    tsum[t] = s01;
    __syncthreads();
    for (int off = 1; off < 256; off <<= 1) {
        int v = (t >= off) ? tsum[t - off] : 0;
        __syncthreads();
        tsum[t] += v;
        __syncthreads();
    }
    int st0 = tsum[t] - s01;                 // exclusive start of bucket 2t
    cnt[2 * t] = st0;                        // cnt[] now = start[]
    cnt[2 * t + 1] = st0 + c0;
    lcur[2 * t] = st0;
    lcur[2 * t + 1] = st0 + c0;
    addb[2 * t] -= st0;                      // addbase = gbase - start
    addb[2 * t + 1] -= (st0 + c0);
    __syncthreads();

    // pass 2: counting-sort chunk into LDS
    for (int i = lo + 4 * t; i < len4; i += 1024) {
        uint4 d4 = *(const uint4*)(dst + i);
        uint4 s4 = *(const uint4*)(src + i);
        unsigned dd[4] = {d4.x, d4.y, d4.z, d4.w};
        unsigned ss[4] = {s4.x, s4.y, s4.z, s4.w};
#pragma unroll
        for (int u = 0; u < 4; ++u) {
            unsigned b = dd[u] >> SBSH;
            int pos = atomicAdd(&lcur[b], 1);
            sorted[pos] = ((dd[u] & (SBN - 1u)) << 19) | ss[u];
            sbuck[pos] = (unsigned short)b;
        }
    }
    for (int i = len4 + t; i < hi; i += 256) {
        unsigned d = (unsigned)dst[i], s = (unsigned)src[i];
        unsigned b = d >> SBSH;
        int pos = atomicAdd(&lcur[b], 1);
        sorted[pos] = ((d & (SBN - 1u)) << 19) | s;
        sbuck[pos] = (unsigned short)b;
    }
    __syncthreads();

    // pass 3: coalesced flush — consecutive i within a bucket hit consecutive
    // global addresses, so a wave's stores form ~8-word contiguous runs.
    for (int i = t; i < len; i += 256) {
        unsigned p = sorted[i];
        int b = sbuck[i];
        staged[(size_t)b * CAP + addb[b] + i] = p;
    }
}

// ---------------- passB: per-super-bucket CSR, rows src-chunk-ordered ----------------
__global__ __launch_bounds__(PBT) void passB_kernel(const unsigned int* __restrict__ staged,
                                                    const int* __restrict__ gcnt,
                                                    unsigned int* __restrict__ eidx,
                                                    int* __restrict__ row_beg,
                                                    int* __restrict__ row_end,
                                                    float* __restrict__ dinv,
                                                    const float* __restrict__ x,
                                                    __half* __restrict__ y1h,
                                                    uint2* __restrict__ coff8) {
    __shared__ int bins[NBIN];                // 32 KB
    __shared__ int tsum[PBT];
    const int t = threadIdx.x;
    const int g = blockIdx.x;
    const int len = gcnt[g];
    const int rb = g * CAP;

    for (int i = t; i < NBIN; i += PBT) bins[i] = 0;
    __syncthreads();

    // histogram over 8192 (dst_low, src_chunk) bins
    int len4 = len & ~3;
    for (int k = 4 * t; k < len4; k += 4 * PBT) {
        uint4 p4 = *(const uint4*)(staged + rb + k);
        atomicAdd(&bins[BIN(p4.x)], 1);
        atomicAdd(&bins[BIN(p4.y)], 1);
        atomicAdd(&bins[BIN(p4.z)], 1);
        atomicAdd(&bins[BIN(p4.w)], 1);
    }
    for (int k = len4 + t; k < len; k += PBT) atomicAdd(&bins[BIN(staged[rb + k])], 1);
    __syncthreads();

    // in-place exclusive scan of 8192 bins (16 per thread + block scan)
    int base_ = 16 * t;
    int run = 0;
#pragma unroll
    for (int j = 0; j < 16; ++j) {
        int c = bins[base_ + j];
        bins[base_ + j] = run;
        run += c;
    }
    tsum[t] = run;
    __syncthreads();
    for (int off = 1; off < PBT; off <<= 1) {
        int v = (t >= off) ? tsum[t - off] : 0;
        __syncthreads();
        tsum[t] += v;
        __syncthreads();
    }
    int off0 = tsum[t] - run;
#pragma unroll
    for (int j = 0; j < 16; ++j) bins[base_ + j] += off0;
    __syncthreads();

    // emit row data (before bins mutate as cursors)
    for (int l = t; l < SBN; l += PBT) {
        int v = (g << SBSH) + l;
        if (v < NNODES) {
            int b0 = bins[8 * l];
            int b1 = (l == SBN - 1) ? len : bins[8 * l + 8];
            row_beg[v] = rb + b0;
            row_end[v] = rb + b1;
            float di = rsqrtf((float)(b1 - b0) + 1.0f);
            dinv[v] = di;
            union { uint2 u; __half2 h[2]; } st;
            st.h[0] = __floats2half2_rn(di * x[3 * v + 0], di * x[3 * v + 1]);
            st.h[1] = __floats2half2_rn(di * x[3 * v + 2], 0.0f);
            *(uint2*)(y1h + 4 * (size_t)v) = st.u;
            // pack per-chunk start deltas (chunk 0 delta is 0)
            union { unsigned char b[8]; uint2 u; } pk;
            pk.b[0] = 0;
#pragma unroll
            for (int c = 1; c < 8; ++c) {
                int d = bins[8 * l + c] - b0;
                pk.b[c] = (unsigned char)(d > 255 ? 255 : d);
            }
            coff8[v] = pk.u;
        }
    }
    __syncthreads();

    // scatter to exact positions (writes stay in the 68 KB L2-resident window)
    for (int k = 4 * t; k < len4; k += 4 * PBT) {
        uint4 p4 = *(const uint4*)(staged + rb + k);
        unsigned pp[4] = {p4.x, p4.y, p4.z, p4.w};
#pragma unroll
        for (int u = 0; u < 4; ++u) {
            int pos = atomicAdd(&bins[BIN(pp[u])], 1);
            eidx[rb + pos] = pp[u] & 0x7FFFFu;
        }
    }
    for (int k = len4 + t; k < len; k += PBT) {
        unsigned p = staged[rb + k];
        int pos = atomicAdd(&bins[BIN(p)], 1);
        eidx[rb + pos] = p & 0x7FFFFu;
    }
}

// ---------------- layer 1: dual-node register accumulation + fused transform ----------------
// 2 nodes/thread with INTERLEAVED cursors (R7's MLP trick). Safe here, unlike
// agg2: the gather table y1h is 4 MB total and fits entirely in each per-XCD
// L2 — no sliding window, no cross-block phase coherence to protect.
__device__ __forceinline__ void acc1(const __half* __restrict__ y1h, unsigned e,
                                     float& a0, float& a1, float& a2) {
    union { uint2 u2; __half2 h[2]; } g;
    g.u2 = *(const uint2*)(y1h + 4 * (size_t)e);
    float2 p01 = __half22float2(g.h[0]);
    float2 p23 = __half22float2(g.h[1]);
    a0 += p01.x; a1 += p01.y; a2 += p23.x;
}

__device__ __forceinline__ int drain1(const unsigned int* __restrict__ eidx,
                                      const __half* __restrict__ y1h,
                                      int i, int end, float& a0, float& a1, float& a2) {
    for (; i + 3 < end; i += 4) {
        unsigned e0 = eidx[i], e1 = eidx[i + 1], e2 = eidx[i + 2], e3 = eidx[i + 3];
        uint2 w0 = *(const uint2*)(y1h + 4 * (size_t)e0);
        uint2 w1 = *(const uint2*)(y1h + 4 * (size_t)e1);
        uint2 w2 = *(const uint2*)(y1h + 4 * (size_t)e2);
        uint2 w3 = *(const uint2*)(y1h + 4 * (size_t)e3);
        uint2 ww[4] = {w0, w1, w2, w3};
#pragma unroll
        for (int u = 0; u < 4; ++u) {
            union { uint2 u2; __half2 h[2]; } g; g.u2 = ww[u];
            float2 p01 = __half22float2(g.h[0]);
            float2 p23 = __half22float2(g.h[1]);
            a0 += p01.x; a1 += p01.y; a2 += p23.x;
        }
    }
    for (; i < end; ++i) acc1(y1h, eidx[i], a0, a1, a2);
    return i;
}

__device__ __forceinline__ void finish1(float a0, float a1, float a2, float di,
                                        const float* __restrict__ W1,
                                        const float* __restrict__ b1,
                                        __half* __restrict__ y2h, int v) {
    a0 *= di; a1 *= di; a2 *= di;
    float hf[16];
#pragma unroll
    for (int j = 0; j < 16; ++j) {
        float h = b1[j] + a0 * W1[j] + a1 * W1[16 + j] + a2 * W1[32 + j];
        hf[j] = di * fmaxf(h, 0.0f);
    }
    union { uint4 u[2]; __half2 h[8]; } st;
#pragma unroll
    for (int q = 0; q < 8; ++q) st.h[q] = __floats2half2_rn(hf[2 * q], hf[2 * q + 1]);
    uint4* dp = (uint4*)(y2h + 16 * (size_t)v);
    dp[0] = st.u[0];
    dp[1] = st.u[1];
}

__global__ __launch_bounds__(256) void agg1t1_kernel(const unsigned int* __restrict__ eidx,
                                                     const int* __restrict__ row_beg,
                                                     const int* __restrict__ row_end,
                                                     const __half* __restrict__ y1h,
                                                     const float* __restrict__ dinv,
                                                     const float* __restrict__ W1,
                                                     const float* __restrict__ b1,
                                                     __half* __restrict__ y2h, int n) {
    const int t = threadIdx.x;
    const int v0 = blockIdx.x * 512 + t;
    const int v1 = v0 + 256;
    const bool ok0 = v0 < n;
    const bool ok1 = v1 < n;

    float a00 = 0.f, a01 = 0.f, a02 = 0.f;
    float a10 = 0.f, a11 = 0.f, a12 = 0.f;
    int i0 = 0, e0 = 0, i1 = 0, e1 = 0;
    if (ok0) {
        acc1(y1h, (unsigned)v0, a00, a01, a02);   // self term
        i0 = row_beg[v0]; e0 = row_end[v0];
    }
    if (ok1) {
        acc1(y1h, (unsigned)v1, a10, a11, a12);
        i1 = row_beg[v1]; e1 = row_end[v1];
    }

    // dual-row 2-wide: 4 independent gathers in flight
    while (i0 + 1 < e0 && i1 + 1 < e1) {
        unsigned ea0 = eidx[i0], ea1 = eidx[i0 + 1];
        unsigned eb0 = eidx[i1], eb1 = eidx[i1 + 1];
        uint2 wa0 = *(const uint2*)(y1h + 4 * (size_t)ea0);
        uint2 wa1 = *(const uint2*)(y1h + 4 * (size_t)ea1);
        uint2 wb0 = *(const uint2*)(y1h + 4 * (size_t)eb0);
        uint2 wb1 = *(const uint2*)(y1h + 4 * (size_t)eb1);
        union { uint2 u2; __half2 h[2]; } g;
        g.u2 = wa0; { float2 p = __half22float2(g.h[0]); float2 q = __half22float2(g.h[1]); a00 += p.x; a01 += p.y; a02 += q.x; }
        g.u2 = wa1; { float2 p = __half22float2(g.h[0]); float2 q = __half22float2(g.h[1]); a00 += p.x; a01 += p.y; a02 += q.x; }
        g.u2 = wb0; { float2 p = __half22float2(g.h[0]); float2 q = __half22float2(g.h[1]); a10 += p.x; a11 += p.y; a12 += q.x; }
        g.u2 = wb1; { float2 p = __half22float2(g.h[0]); float2 q = __half22float2(g.h[1]); a10 += p.x; a11 += p.y; a12 += q.x; }
        i0 += 2; i1 += 2;
    }
    // dual-row scalar
    while (i0 < e0 && i1 < e1) {
        unsigned ea = eidx[i0], eb = eidx[i1];
        uint2 wa = *(const uint2*)(y1h + 4 * (size_t)ea);
        uint2 wb = *(const uint2*)(y1h + 4 * (size_t)eb);
        union { uint2 u2; __half2 h[2]; } g;
        g.u2 = wa; { float2 p = __half22float2(g.h[0]); float2 q = __half22float2(g.h[1]); a00 += p.x; a01 += p.y; a02 += q.x; }
        g.u2 = wb; { float2 p = __half22float2(g.h[0]); float2 q = __half22float2(g.h[1]); a10 += p.x; a11 += p.y; a12 += q.x; }
        ++i0; ++i1;
    }
    // drains
    i0 = drain1(eidx, y1h, i0, e0, a00, a01, a02);
    i1 = drain1(eidx, y1h, i1, e1, a10, a11, a12);

    if (ok0) finish1(a00, a01, a02, dinv[v0], W1, b1, y2h, v0);
    if (ok1) finish1(a10, a11, a12, dinv[v1], W1, b1, y2h, v1);
}

// ---------------- layer 2: chunk-synchronized node-centric aggregation ----------------
__device__ __forceinline__ void addh8(float* a, uint4 w) {
    union { uint4 u4; __half2 h[4]; } g; g.u4 = w;
#pragma unroll
    for (int q = 0; q < 4; ++q) {
        float2 f = __half22float2(g.h[q]);
        a[2 * q + 0] += f.x;
        a[2 * q + 1] += f.y;
    }
}

__device__ __forceinline__ int gather_seg(const unsigned int* __restrict__ eidx,
                                          const __half* __restrict__ y2h,
                                          int i, int lim, float* a) {
    for (; i + 3 < lim; i += 4) {
        unsigned e0 = eidx[i], e1 = eidx[i + 1], e2 = eidx[i + 2], e3 = eidx[i + 3];
        const uint4* p0 = (const uint4*)(y2h + 16 * (size_t)e0);
        const uint4* p1 = (const uint4*)(y2h + 16 * (size_t)e1);
        const uint4* p2 = (const uint4*)(y2h + 16 * (size_t)e2);
        const uint4* p3 = (const uint4*)(y2h + 16 * (size_t)e3);
        uint4 w0a = p0[0], w0b = p0[1];
        uint4 w1a = p1[0], w1b = p1[1];
        uint4 w2a = p2[0], w2b = p2[1];
        uint4 w3a = p3[0], w3b = p3[1];
        addh8(a, w0a); addh8(a + 8, w0b);
        addh8(a, w1a); addh8(a + 8, w1b);
        addh8(a, w2a); addh8(a + 8, w2b);
        addh8(a, w3a); addh8(a + 8, w3b);
    }
    for (; i < lim; ++i) {
        unsigned e = eidx[i];
        const uint4* p = (const uint4*)(y2h + 16 * (size_t)e);
        uint4 wa = p[0], wb = p[1];
        addh8(a, wa); addh8(a + 8, wb);
    }
    return i;
}

__device__ __forceinline__ void finish_node(const float* a, float di,
                                            const float* __restrict__ W2,
                                            const float* __restrict__ b2,
                                            float* __restrict__ out, int v) {
    float s16[16];
#pragma unroll
    for (int k = 0; k < 16; ++k) s16[k] = a[k] * di;
    float z[10];
#pragma unroll
    for (int j = 0; j < 10; ++j) {
        float s = b2[j];
#pragma unroll
        for (int k = 0; k < 16; ++k) s += s16[k] * W2[k * 10 + j];
        z[j] = s;
    }
    float m = z[0];
#pragma unroll
    for (int j = 1; j < 10; ++j) m = fmaxf(m, z[j]);
    float sum = 0.0f;
#pragma unroll
    for (int j = 0; j < 10; ++j) sum += expf(z[j] - m);
    float lse = logf(sum);
    float* ov = out + 10 * (size_t)v;
#pragma unroll
    for (int j = 0; j < 10; ++j) ov[j] = z[j] - m - lse;
}

// R3-exact configuration (measured 104 us / 282 MB fetch): one block per
// super-bucket; 512 threads x 2 rows SEQUENTIAL per phase; block barrier
// between the 8 src-chunk phases. Verified bistable-thrash evidence (R4-R8):
// any per-block speedup shortens the sweep, cross-block stagger then spans
// >L2-worth of windows -> fetch 282->370+ MB and NET SLOWDOWN. Grid coherence
// reaches the 213 MB floor but 489 same-word device atomics cost ~73 us/phase.
// DO NOT speed up the per-block inner loop without grid-level pacing.
__global__ __launch_bounds__(512, 4) void agg2t2_kernel(const unsigned int* __restrict__ eidx,
                                                        const int* __restrict__ row_beg,
                                                        const int* __restrict__ row_end,
                                                        const uint2* __restrict__ coff8,
                                                        const __half* __restrict__ y2h,
                                                        const float* __restrict__ dinv,
                                                        const float* __restrict__ W2,
                                                        const float* __restrict__ b2,
                                                        float* __restrict__ out) {
    const int g = blockIdx.x;
    const int t = threadIdx.x;
    const int v0 = (g << SBSH) + t;
    const int v1 = v0 + 512;
    const bool ok0 = v0 < NNODES;
    const bool ok1 = v1 < NNODES;

    float a0[16], a1[16];
#pragma unroll
    for (int k = 0; k < 16; ++k) { a0[k] = 0.0f; a1[k] = 0.0f; }

    int i0 = 0, end0 = 0, i1 = 0, end1 = 0;
    unsigned long long pk0 = 0ull, pk1 = 0ull;
    if (ok0) {
        const uint4* sp = (const uint4*)(y2h + 16 * (size_t)v0);
        uint4 s0 = sp[0], s1 = sp[1];
        addh8(a0, s0); addh8(a0 + 8, s1);
        i0 = row_beg[v0]; end0 = row_end[v0];
        uint2 c = coff8[v0];
        pk0 = ((unsigned long long)c.y << 32) | c.x;
    }
    if (ok1) {
        const uint4* sp = (const uint4*)(y2h + 16 * (size_t)v1);
        uint4 s0 = sp[0], s1 = sp[1];
        addh8(a1, s0); addh8(a1 + 8, s1);
        i1 = row_beg[v1]; end1 = row_end[v1];
        uint2 c = coff8[v1];
        pk1 = ((unsigned long long)c.y << 32) | c.x;
    }
    const int beg0 = i0, beg1 = i1;

    for (int c = 1; c <= 8; ++c) {
        int sh = (8 * c) & 63;
        int lim0 = (c == 8) ? end0 : beg0 + (int)((pk0 >> sh) & 255ull);
        int lim1 = (c == 8) ? end1 : beg1 + (int)((pk1 >> sh) & 255ull);
        i0 = gather_seg(eidx, y2h, i0, lim0, a0);
        i1 = gather_seg(eidx, y2h, i1, lim1, a1);
        if (c < 8) __syncthreads();
    }

    if (ok0) finish_node(a0, dinv[v0], W2, b2, out, v0);
    if (ok1) finish_node(a1, dinv[v1], W2, b2, out, v1);
}

extern "C" void kernel_launch(void* const* d_in, const int* in_sizes, int n_in,
                              void* d_out, int out_size, void* d_ws, size_t ws_size,
                              hipStream_t stream) {
    const float* x  = (const float*)d_in[0];
    const int*   ei = (const int*)d_in[1];
    const float* W1 = (const float*)d_in[2];
    const float* b1 = (const float*)d_in[3];
    const float* W2 = (const float*)d_in[4];
    const float* b2 = (const float*)d_in[5];
    float* out = (float*)d_out;

    const int E = in_sizes[1] / 2;            // 8,000,000
    const int* src = ei;
    const int* dst = ei + E;

    // workspace layout (words)
    int*          ws_i    = (int*)d_ws;
    int*          gcursor = ws_i;                                   // 512
    int*          row_beg = ws_i + 512;                             // N
    int*          row_end = ws_i + 512 + 500000;                    // N
    float*        dinv    = (float*)(ws_i + 512 + 1000000);         // N
    __half*       y1h     = (__half*)(ws_i + 512 + 1500000);        // 4N halves (1M words)
    unsigned int* staged  = (unsigned int*)(ws_i + 512 + 2500000);  // 512*CAP = 8,716,288
    unsigned int* eidx    = staged + (size_t)NSB * CAP;             // 8,716,288
    uint2*        coff8   = (uint2*)(eidx + (size_t)NSB * CAP);     // 524288 * 8 B = 1,048,576 words
    __half*       y2h     = (__half*)staged;                        // overlay: staged dead after passB
    // total ~ 20.98M words = 83.9 MB

    hipMemsetAsync(gcursor, 0, NSB * sizeof(int), stream);

    int nblk = (E + CHUNK - 1) / CHUNK;       // 1954
    scatter_kernel<<<nblk, 256, 0, stream>>>(src, dst, gcursor, staged, E);
    passB_kernel<<<NSB, PBT, 0, stream>>>(staged, gcursor, eidx, row_beg, row_end, dinv, x, y1h, coff8);
    agg1t1_kernel<<<NAGG1, 256, 0, stream>>>(eidx, row_beg, row_end, y1h, dinv, W1, b1, y2h, NNODES);
    agg2t2_kernel<<<NSB, 512, 0, stream>>>(eidx, row_beg, row_end, coff8, y2h, dinv, W2, b2, out);
}

// Round 13
// 384.018 us; speedup vs baseline: 1.0465x; 1.0465x over previous
//
#include <hip/hip_runtime.h>
#include <hip/hip_fp16.h>

#define NNODES    500000
#define SBSH      10            // super-bucket = dst >> 10
#define NSB       512           // super-bucket count (covers 524288 >= N)
#define SBN       1024          // nodes per super-bucket
#define CAP       17024         // staged region words (mean 15625, +11 sigma), mult of 16
#define CHUNK     4096          // edges per scatter block
#define NAGG      1954          // ceil(N/256) — agg1 grid, 1 node/thread (max TLP; R12 proved 2/thread loses)
#define NBIN      8192          // passB bins: dst_low10 * 8 + src_high3
#define PBT       1024          // passB threads per block (512 -> 1024: 16 -> 32 waves/CU)
#define PBS       (NBIN / PBT)  // scan bins per thread (8)

// bin key: group rows by dst, order within row by src-chunk (2 MB y2h windows)
#define BIN(p) ((int)(((p) >> 19) * 8u + (((p) & 0x7FFFFu) >> 16)))

// ---------------- pass 1: coarse scatter, LDS counting-sort + coalesced flush ----------------
__global__ __launch_bounds__(256) void scatter_kernel(const int* __restrict__ src,
                                                      const int* __restrict__ dst,
                                                      int* __restrict__ gcursor,
                                                      unsigned int* __restrict__ staged, int E) {
    __shared__ int cnt[NSB];                 // histogram -> start[] after scan
    __shared__ int addb[NSB];                // global seg base -> addbase = gbase - start
    __shared__ int lcur[NSB];                // LDS sort cursors
    __shared__ int tsum[256];
    __shared__ unsigned int sorted[CHUNK];   // 16 KB payloads, bucket-ordered
    __shared__ unsigned short sbuck[CHUNK];  // 8 KB bucket id per slot

    const int t = threadIdx.x;
    for (int i = t; i < NSB; i += 256) cnt[i] = 0;
    __syncthreads();

    const int lo = blockIdx.x * CHUNK;
    const int hi = min(E, lo + CHUNK);
    const int len = hi - lo;
    const int len4 = lo + (len & ~3);

    // pass 1: bucket histogram
    for (int i = lo + 4 * t; i < len4; i += 1024) {
        uint4 d4 = *(const uint4*)(dst + i);
        atomicAdd(&cnt[d4.x >> SBSH], 1);
        atomicAdd(&cnt[d4.y >> SBSH], 1);
        atomicAdd(&cnt[d4.z >> SBSH], 1);
        atomicAdd(&cnt[d4.w >> SBSH], 1);
    }
    for (int i = len4 + t; i < hi; i += 256)
        atomicAdd(&cnt[((unsigned)dst[i]) >> SBSH], 1);
    __syncthreads();

    // reserve global segments (one atomic per nonzero bucket per block)
    for (int b = t; b < NSB; b += 256) {
        int c = cnt[b];
        addb[b] = c ? atomicAdd(&gcursor[b], c) : 0;
    }
    __syncthreads();

    // exclusive scan of 512 counts (2 per thread + block scan over partials)
    int c0 = cnt[2 * t], c1 = cnt[2 * t + 1];
    int s01 = c0 + c1;
    tsum[t] = s01;
    __syncthreads();
    for (int off = 1; off < 256; off <<= 1) {
        int v = (t >= off) ? tsum[t - off] : 0;
        __syncthreads();
        tsum[t] += v;
        __syncthreads();
    }
    int st0 = tsum[t] - s01;                 // exclusive start of bucket 2t
    cnt[2 * t] = st0;                        // cnt[] now = start[]
    cnt[2 * t + 1] = st0 + c0;
    lcur[2 * t] = st0;
    lcur[2 * t + 1] = st0 + c0;
    addb[2 * t] -= st0;                      // addbase = gbase - start
    addb[2 * t + 1] -= (st0 + c0);
    __syncthreads();

    // pass 2: counting-sort chunk into LDS
    for (int i = lo + 4 * t; i < len4; i += 1024) {
        uint4 d4 = *(const uint4*)(dst + i);
        uint4 s4 = *(const uint4*)(src + i);
        unsigned dd[4] = {d4.x, d4.y, d4.z, d4.w};
        unsigned ss[4] = {s4.x, s4.y, s4.z, s4.w};
#pragma unroll
        for (int u = 0; u < 4; ++u) {
            unsigned b = dd[u] >> SBSH;
            int pos = atomicAdd(&lcur[b], 1);
            sorted[pos] = ((dd[u] & (SBN - 1u)) << 19) | ss[u];
            sbuck[pos] = (unsigned short)b;
        }
    }
    for (int i = len4 + t; i < hi; i += 256) {
        unsigned d = (unsigned)dst[i], s = (unsigned)src[i];
        unsigned b = d >> SBSH;
        int pos = atomicAdd(&lcur[b], 1);
        sorted[pos] = ((d & (SBN - 1u)) << 19) | s;
        sbuck[pos] = (unsigned short)b;
    }
    __syncthreads();

    // pass 3: coalesced flush — consecutive i within a bucket hit consecutive
    // global addresses, so a wave's stores form ~8-word contiguous runs.
    for (int i = t; i < len; i += 256) {
        unsigned p = sorted[i];
        int b = sbuck[i];
        staged[(size_t)b * CAP + addb[b] + i] = p;
    }
}

// ---------------- passB: per-super-bucket CSR, rows src-chunk-ordered ----------------
// Grid pinned at NSB=512 blocks (one per super-bucket) -> block width is the
// only occupancy lever. 256->512 threads measured +39 us (R11); now 512->1024
// (32 waves/CU). LDS 36 KB x 2 blocks/CU = 72 KB, fits.
__global__ __launch_bounds__(PBT) void passB_kernel(const unsigned int* __restrict__ staged,
                                                    const int* __restrict__ gcnt,
                                                    unsigned int* __restrict__ eidx,
                                                    int* __restrict__ row_beg,
                                                    int* __restrict__ row_end,
                                                    float* __restrict__ dinv,
                                                    const float* __restrict__ x,
                                                    __half* __restrict__ y1h,
                                                    uint2* __restrict__ coff8) {
    __shared__ int bins[NBIN];                // 32 KB
    __shared__ int tsum[PBT];                 // 4 KB
    const int t = threadIdx.x;
    const int g = blockIdx.x;
    const int len = gcnt[g];
    const int rb = g * CAP;

    for (int i = t; i < NBIN; i += PBT) bins[i] = 0;
    __syncthreads();

    // histogram over 8192 (dst_low, src_chunk) bins
    int len4 = len & ~3;
    for (int k = 4 * t; k < len4; k += 4 * PBT) {
        uint4 p4 = *(const uint4*)(staged + rb + k);
        atomicAdd(&bins[BIN(p4.x)], 1);
        atomicAdd(&bins[BIN(p4.y)], 1);
        atomicAdd(&bins[BIN(p4.z)], 1);
        atomicAdd(&bins[BIN(p4.w)], 1);
    }
    for (int k = len4 + t; k < len; k += PBT) atomicAdd(&bins[BIN(staged[rb + k])], 1);
    __syncthreads();

    // in-place exclusive scan of 8192 bins (PBS per thread + block scan)
    int base_ = PBS * t;
    int run = 0;
#pragma unroll
    for (int j = 0; j < PBS; ++j) {
        int c = bins[base_ + j];
        bins[base_ + j] = run;
        run += c;
    }
    tsum[t] = run;
    __syncthreads();
    for (int off = 1; off < PBT; off <<= 1) {
        int v = (t >= off) ? tsum[t - off] : 0;
        __syncthreads();
        tsum[t] += v;
        __syncthreads();
    }
    int off0 = tsum[t] - run;
#pragma unroll
    for (int j = 0; j < PBS; ++j) bins[base_ + j] += off0;
    __syncthreads();

    // emit row data (before bins mutate as cursors)
    for (int l = t; l < SBN; l += PBT) {
        int v = (g << SBSH) + l;
        if (v < NNODES) {
            int b0 = bins[8 * l];
            int b1 = (l == SBN - 1) ? len : bins[8 * l + 8];
            row_beg[v] = rb + b0;
            row_end[v] = rb + b1;
            float di = rsqrtf((float)(b1 - b0) + 1.0f);
            dinv[v] = di;
            union { uint2 u; __half2 h[2]; } st;
            st.h[0] = __floats2half2_rn(di * x[3 * v + 0], di * x[3 * v + 1]);
            st.h[1] = __floats2half2_rn(di * x[3 * v + 2], 0.0f);
            *(uint2*)(y1h + 4 * (size_t)v) = st.u;
            // pack per-chunk start deltas (chunk 0 delta is 0)
            union { unsigned char b[8]; uint2 u; } pk;
            pk.b[0] = 0;
#pragma unroll
            for (int c = 1; c < 8; ++c) {
                int d = bins[8 * l + c] - b0;
                pk.b[c] = (unsigned char)(d > 255 ? 255 : d);
            }
            coff8[v] = pk.u;
        }
    }
    __syncthreads();

    // scatter to exact positions (writes stay in the 68 KB L2-resident window)
    for (int k = 4 * t; k < len4; k += 4 * PBT) {
        uint4 p4 = *(const uint4*)(staged + rb + k);
        unsigned pp[4] = {p4.x, p4.y, p4.z, p4.w};
#pragma unroll
        for (int u = 0; u < 4; ++u) {
            int pos = atomicAdd(&bins[BIN(pp[u])], 1);
            eidx[rb + pos] = pp[u] & 0x7FFFFu;
        }
    }
    for (int k = len4 + t; k < len; k += PBT) {
        unsigned p = staged[rb + k];
        int pos = atomicAdd(&bins[BIN(p)], 1);
        eidx[rb + pos] = p & 0x7FFFFu;
    }
}

// ---------------- layer 1: node-centric register accumulation + fused transform ----------------
// R11-exact: 1 node/thread, 500K threads (max TLP). R12 proved 2 nodes/thread
// (250K threads) loses ~19 us: on a latency-bound gather with free thread
// count, TLP beats ILP.
__global__ __launch_bounds__(256) void agg1t1_kernel(const unsigned int* __restrict__ eidx,
                                                     const int* __restrict__ row_beg,
                                                     const int* __restrict__ row_end,
                                                     const __half* __restrict__ y1h,
                                                     const float* __restrict__ dinv,
                                                     const float* __restrict__ W1,
                                                     const float* __restrict__ b1,
                                                     __half* __restrict__ y2h, int n) {
    int v = blockIdx.x * 256 + threadIdx.x;
    if (v >= n) return;
    int beg = row_beg[v], end = row_end[v];
    union { uint2 u2; __half2 h[2]; } sf;
    sf.u2 = *(const uint2*)(y1h + 4 * (size_t)v);
    float2 f01 = __half22float2(sf.h[0]);
    float2 f23 = __half22float2(sf.h[1]);
    float a0 = f01.x, a1 = f01.y, a2 = f23.x;
    int i = beg;
    for (; i + 3 < end; i += 4) {
        unsigned e0 = eidx[i], e1 = eidx[i + 1], e2 = eidx[i + 2], e3 = eidx[i + 3];
        uint2 w0 = *(const uint2*)(y1h + 4 * (size_t)e0);
        uint2 w1 = *(const uint2*)(y1h + 4 * (size_t)e1);
        uint2 w2 = *(const uint2*)(y1h + 4 * (size_t)e2);
        uint2 w3 = *(const uint2*)(y1h + 4 * (size_t)e3);
        uint2 ww[4] = {w0, w1, w2, w3};
#pragma unroll
        for (int u = 0; u < 4; ++u) {
            union { uint2 u2; __half2 h[2]; } g; g.u2 = ww[u];
            float2 p01 = __half22float2(g.h[0]);
            float2 p23 = __half22float2(g.h[1]);
            a0 += p01.x; a1 += p01.y; a2 += p23.x;
        }
    }
    for (; i < end; ++i) {
        unsigned e = eidx[i];
        union { uint2 u2; __half2 h[2]; } g;
        g.u2 = *(const uint2*)(y1h + 4 * (size_t)e);
        float2 p01 = __half22float2(g.h[0]);
        float2 p23 = __half22float2(g.h[1]);
        a0 += p01.x; a1 += p01.y; a2 += p23.x;
    }
    float di = dinv[v];
    a0 *= di; a1 *= di; a2 *= di;
    float hf[16];
#pragma unroll
    for (int j = 0; j < 16; ++j) {
        float h = b1[j] + a0 * W1[j] + a1 * W1[16 + j] + a2 * W1[32 + j];
        hf[j] = di * fmaxf(h, 0.0f);
    }
    union { uint4 u[2]; __half2 h[8]; } st;
#pragma unroll
    for (int q = 0; q < 8; ++q) st.h[q] = __floats2half2_rn(hf[2 * q], hf[2 * q + 1]);
    uint4* dp = (uint4*)(y2h + 16 * (size_t)v);
    dp[0] = st.u[0];
    dp[1] = st.u[1];
}

// ---------------- layer 2: chunk-synchronized node-centric aggregation ----------------
__device__ __forceinline__ void addh8(float* a, uint4 w) {
    union { uint4 u4; __half2 h[4]; } g; g.u4 = w;
#pragma unroll
    for (int q = 0; q < 4; ++q) {
        float2 f = __half22float2(g.h[q]);
        a[2 * q + 0] += f.x;
        a[2 * q + 1] += f.y;
    }
}

__device__ __forceinline__ int gather_seg(const unsigned int* __restrict__ eidx,
                                          const __half* __restrict__ y2h,
                                          int i, int lim, float* a) {
    for (; i + 3 < lim; i += 4) {
        unsigned e0 = eidx[i], e1 = eidx[i + 1], e2 = eidx[i + 2], e3 = eidx[i + 3];
        const uint4* p0 = (const uint4*)(y2h + 16 * (size_t)e0);
        const uint4* p1 = (const uint4*)(y2h + 16 * (size_t)e1);
        const uint4* p2 = (const uint4*)(y2h + 16 * (size_t)e2);
        const uint4* p3 = (const uint4*)(y2h + 16 * (size_t)e3);
        uint4 w0a = p0[0], w0b = p0[1];
        uint4 w1a = p1[0], w1b = p1[1];
        uint4 w2a = p2[0], w2b = p2[1];
        uint4 w3a = p3[0], w3b = p3[1];
        addh8(a, w0a); addh8(a + 8, w0b);
        addh8(a, w1a); addh8(a + 8, w1b);
        addh8(a, w2a); addh8(a + 8, w2b);
        addh8(a, w3a); addh8(a + 8, w3b);
    }
    for (; i < lim; ++i) {
        unsigned e = eidx[i];
        const uint4* p = (const uint4*)(y2h + 16 * (size_t)e);
        uint4 wa = p[0], wb = p[1];
        addh8(a, wa); addh8(a + 8, wb);
    }
    return i;
}

__device__ __forceinline__ void finish_node(const float* a, float di,
                                            const float* __restrict__ W2,
                                            const float* __restrict__ b2,
                                            float* __restrict__ out, int v) {
    float s16[16];
#pragma unroll
    for (int k = 0; k < 16; ++k) s16[k] = a[k] * di;
    float z[10];
#pragma unroll
    for (int j = 0; j < 10; ++j) {
        float s = b2[j];
#pragma unroll
        for (int k = 0; k < 16; ++k) s += s16[k] * W2[k * 10 + j];
        z[j] = s;
    }
    float m = z[0];
#pragma unroll
    for (int j = 1; j < 10; ++j) m = fmaxf(m, z[j]);
    float sum = 0.0f;
#pragma unroll
    for (int j = 0; j < 10; ++j) sum += expf(z[j] - m);
    float lse = logf(sum);
    float* ov = out + 10 * (size_t)v;
#pragma unroll
    for (int j = 0; j < 10; ++j) ov[j] = z[j] - m - lse;
}

// R3-exact configuration (measured 104 us / 282 MB fetch): one block per
// super-bucket; 512 threads x 2 rows SEQUENTIAL per phase; block barrier
// between the 8 src-chunk phases. Verified bistable-thrash evidence (R4-R8):
// any per-block speedup shortens the sweep, cross-block stagger then spans
// >L2-worth of windows -> fetch 282->370+ MB and NET SLOWDOWN. Grid coherence
// reaches the 213 MB floor but 489 same-word device atomics cost ~73 us/phase.
// DO NOT speed up the per-block inner loop without grid-level pacing.
__global__ __launch_bounds__(512, 4) void agg2t2_kernel(const unsigned int* __restrict__ eidx,
                                                        const int* __restrict__ row_beg,
                                                        const int* __restrict__ row_end,
                                                        const uint2* __restrict__ coff8,
                                                        const __half* __restrict__ y2h,
                                                        const float* __restrict__ dinv,
                                                        const float* __restrict__ W2,
                                                        const float* __restrict__ b2,
                                                        float* __restrict__ out) {
    const int g = blockIdx.x;
    const int t = threadIdx.x;
    const int v0 = (g << SBSH) + t;
    const int v1 = v0 + 512;
    const bool ok0 = v0 < NNODES;
    const bool ok1 = v1 < NNODES;

    float a0[16], a1[16];
#pragma unroll
    for (int k = 0; k < 16; ++k) { a0[k] = 0.0f; a1[k] = 0.0f; }

    int i0 = 0, end0 = 0, i1 = 0, end1 = 0;
    unsigned long long pk0 = 0ull, pk1 = 0ull;
    if (ok0) {
        const uint4* sp = (const uint4*)(y2h + 16 * (size_t)v0);
        uint4 s0 = sp[0], s1 = sp[1];
        addh8(a0, s0); addh8(a0 + 8, s1);
        i0 = row_beg[v0]; end0 = row_end[v0];
        uint2 c = coff8[v0];
        pk0 = ((unsigned long long)c.y << 32) | c.x;
    }
    if (ok1) {
        const uint4* sp = (const uint4*)(y2h + 16 * (size_t)v1);
        uint4 s0 = sp[0], s1 = sp[1];
        addh8(a1, s0); addh8(a1 + 8, s1);
        i1 = row_beg[v1]; end1 = row_end[v1];
        uint2 c = coff8[v1];
        pk1 = ((unsigned long long)c.y << 32) | c.x;
    }
    const int beg0 = i0, beg1 = i1;

    for (int c = 1; c <= 8; ++c) {
        int sh = (8 * c) & 63;
        int lim0 = (c == 8) ? end0 : beg0 + (int)((pk0 >> sh) & 255ull);
        int lim1 = (c == 8) ? end1 : beg1 + (int)((pk1 >> sh) & 255ull);
        i0 = gather_seg(eidx, y2h, i0, lim0, a0);
        i1 = gather_seg(eidx, y2h, i1, lim1, a1);
        if (c < 8) __syncthreads();
    }

    if (ok0) finish_node(a0, dinv[v0], W2, b2, out, v0);
    if (ok1) finish_node(a1, dinv[v1], W2, b2, out, v1);
}

extern "C" void kernel_launch(void* const* d_in, const int* in_sizes, int n_in,
                              void* d_out, int out_size, void* d_ws, size_t ws_size,
                              hipStream_t stream) {
    const float* x  = (const float*)d_in[0];
    const int*   ei = (const int*)d_in[1];
    const float* W1 = (const float*)d_in[2];
    const float* b1 = (const float*)d_in[3];
    const float* W2 = (const float*)d_in[4];
    const float* b2 = (const float*)d_in[5];
    float* out = (float*)d_out;

    const int E = in_sizes[1] / 2;            // 8,000,000
    const int* src = ei;
    const int* dst = ei + E;

    // workspace layout (words)
    int*          ws_i    = (int*)d_ws;
    int*          gcursor = ws_i;                                   // 512
    int*          row_beg = ws_i + 512;                             // N
    int*          row_end = ws_i + 512 + 500000;                    // N
    float*        dinv    = (float*)(ws_i + 512 + 1000000);         // N
    __half*       y1h     = (__half*)(ws_i + 512 + 1500000);        // 4N halves (1M words)
    unsigned int* staged  = (unsigned int*)(ws_i + 512 + 2500000);  // 512*CAP = 8,716,288
    unsigned int* eidx    = staged + (size_t)NSB * CAP;             // 8,716,288
    uint2*        coff8   = (uint2*)(eidx + (size_t)NSB * CAP);     // 524288 * 8 B = 1,048,576 words
    __half*       y2h     = (__half*)staged;                        // overlay: staged dead after passB
    // total ~ 20.98M words = 83.9 MB

    hipMemsetAsync(gcursor, 0, NSB * sizeof(int), stream);

    int nblk = (E + CHUNK - 1) / CHUNK;       // 1954
    scatter_kernel<<<nblk, 256, 0, stream>>>(src, dst, gcursor, staged, E);
    passB_kernel<<<NSB, PBT, 0, stream>>>(staged, gcursor, eidx, row_beg, row_end, dinv, x, y1h, coff8);
    agg1t1_kernel<<<NAGG, 256, 0, stream>>>(eidx, row_beg, row_end, y1h, dinv, W1, b1, y2h, NNODES);
    agg2t2_kernel<<<NSB, 512, 0, stream>>>(eidx, row_beg, row_end, coff8, y2h, dinv, W2, b2, out);
}

// Round 15
// 360.538 us; speedup vs baseline: 1.1147x; 1.0651x over previous
//
#include <hip/hip_runtime.h>
#include <hip/hip_fp16.h>

#define NNODES    500000
#define SBSH      10            // super-bucket = dst >> 10
#define NSB       512           // super-bucket count (covers 524288 >= N)
#define SBN       1024          // nodes per super-bucket
#define CAP       17024         // staged region words (mean 15625, +11 sigma), mult of 16
#define CHUNK     8192          // edges per scatter block (4096->8192: half the scan/barrier overhead)
#define SCT       512           // scatter threads per block
#define NAGG      1954          // ceil(N/256) — agg1 grid, 1 node/thread (max TLP; R12 proved 2/thread loses)
#define NBIN      8192          // passB bins: dst_low10 * 8 + src_high3
#define PBT       1024          // passB threads per block
#define PBS       (NBIN / PBT)  // scan bins per thread (8)

// bin key: group rows by dst, order within row by src-chunk (2 MB y2h windows)
#define BIN(p) ((int)(((p) >> 19) * 8u + (((p) & 0x7FFFFu) >> 16)))

// ---------------- pass 1: coarse scatter, LDS counting-sort + coalesced flush ----------------
// CHUNK=8192 @ 512 threads: same 16 edges/thread as before, but half the
// blocks -> half the scans/reserves/barriers, and mean bucket run in the
// flush doubles to ~16 words -> full 64B-line stores. LDS 56 KB, 2 blocks/CU.
__global__ __launch_bounds__(SCT) void scatter_kernel(const int* __restrict__ src,
                                                      const int* __restrict__ dst,
                                                      int* __restrict__ gcursor,
                                                      unsigned int* __restrict__ staged, int E) {
    __shared__ int cnt[NSB];                 // histogram -> start[] after scan
    __shared__ int addb[NSB];                // global seg base -> addbase = gbase - start
    __shared__ int lcur[NSB];                // LDS sort cursors
    __shared__ int tsum[SCT];
    __shared__ unsigned int sorted[CHUNK];   // 32 KB payloads, bucket-ordered
    __shared__ unsigned short sbuck[CHUNK];  // 16 KB bucket id per slot

    const int t = threadIdx.x;
    cnt[t] = 0;                              // SCT == NSB: one bucket per thread
    __syncthreads();

    const int lo = blockIdx.x * CHUNK;
    const int hi = min(E, lo + CHUNK);
    const int len = hi - lo;
    const int len4 = lo + (len & ~3);

    // pass 1: bucket histogram
    for (int i = lo + 4 * t; i < len4; i += 4 * SCT) {
        uint4 d4 = *(const uint4*)(dst + i);
        atomicAdd(&cnt[d4.x >> SBSH], 1);
        atomicAdd(&cnt[d4.y >> SBSH], 1);
        atomicAdd(&cnt[d4.z >> SBSH], 1);
        atomicAdd(&cnt[d4.w >> SBSH], 1);
    }
    for (int i = len4 + t; i < hi; i += SCT)
        atomicAdd(&cnt[((unsigned)dst[i]) >> SBSH], 1);
    __syncthreads();

    // reserve global segment for this block's share of each bucket
    int c0 = cnt[t];
    addb[t] = c0 ? atomicAdd(&gcursor[t], c0) : 0;

    // exclusive scan of 512 counts (1 per thread + block scan)
    tsum[t] = c0;
    __syncthreads();
    for (int off = 1; off < SCT; off <<= 1) {
        int v = (t >= off) ? tsum[t - off] : 0;
        __syncthreads();
        tsum[t] += v;
        __syncthreads();
    }
    int st0 = tsum[t] - c0;                  // exclusive start of bucket t
    cnt[t] = st0;                            // cnt[] now = start[]
    lcur[t] = st0;
    addb[t] -= st0;                          // addbase = gbase - start
    __syncthreads();

    // pass 2: counting-sort chunk into LDS
    for (int i = lo + 4 * t; i < len4; i += 4 * SCT) {
        uint4 d4 = *(const uint4*)(dst + i);
        uint4 s4 = *(const uint4*)(src + i);
        unsigned dd[4] = {d4.x, d4.y, d4.z, d4.w};
        unsigned ss[4] = {s4.x, s4.y, s4.z, s4.w};
#pragma unroll
        for (int u = 0; u < 4; ++u) {
            unsigned b = dd[u] >> SBSH;
            int pos = atomicAdd(&lcur[b], 1);
            sorted[pos] = ((dd[u] & (SBN - 1u)) << 19) | ss[u];
            sbuck[pos] = (unsigned short)b;
        }
    }
    for (int i = len4 + t; i < hi; i += SCT) {
        unsigned d = (unsigned)dst[i], s = (unsigned)src[i];
        unsigned b = d >> SBSH;
        int pos = atomicAdd(&lcur[b], 1);
        sorted[pos] = ((d & (SBN - 1u)) << 19) | s;
        sbuck[pos] = (unsigned short)b;
    }
    __syncthreads();

    // pass 3: coalesced flush — consecutive i within a bucket hit consecutive
    // global addresses; runs average ~16 words -> full-line stores.
    for (int i = t; i < len; i += SCT) {
        unsigned p = sorted[i];
        int b = sbuck[i];
        staged[(size_t)b * CAP + addb[b] + i] = p;
    }
}

// ---------------- passB: per-super-bucket CSR, rows src-chunk-ordered ----------------
__global__ __launch_bounds__(PBT) void passB_kernel(const unsigned int* __restrict__ staged,
                                                    const int* __restrict__ gcnt,
                                                    unsigned int* __restrict__ eidx,
                                                    int* __restrict__ row_beg,
                                                    int* __restrict__ row_end,
                                                    float* __restrict__ dinv,
                                                    const float* __restrict__ x,
                                                    __half* __restrict__ y1h,
                                                    uint2* __restrict__ coff8) {
    __shared__ int bins[NBIN];                // 32 KB
    __shared__ int tsum[PBT];                 // 4 KB
    const int t = threadIdx.x;
    const int g = blockIdx.x;
    const int len = gcnt[g];
    const int rb = g * CAP;

    for (int i = t; i < NBIN; i += PBT) bins[i] = 0;
    __syncthreads();

    // histogram over 8192 (dst_low, src_chunk) bins
    int len4 = len & ~3;
    for (int k = 4 * t; k < len4; k += 4 * PBT) {
        uint4 p4 = *(const uint4*)(staged + rb + k);
        atomicAdd(&bins[BIN(p4.x)], 1);
        atomicAdd(&bins[BIN(p4.y)], 1);
        atomicAdd(&bins[BIN(p4.z)], 1);
        atomicAdd(&bins[BIN(p4.w)], 1);
    }
    for (int k = len4 + t; k < len; k += PBT) atomicAdd(&bins[BIN(staged[rb + k])], 1);
    __syncthreads();

    // in-place exclusive scan of 8192 bins (PBS per thread + block scan)
    int base_ = PBS * t;
    int run = 0;
#pragma unroll
    for (int j = 0; j < PBS; ++j) {
        int c = bins[base_ + j];
        bins[base_ + j] = run;
        run += c;
    }
    tsum[t] = run;
    __syncthreads();
    for (int off = 1; off < PBT; off <<= 1) {
        int v = (t >= off) ? tsum[t - off] : 0;
        __syncthreads();
        tsum[t] += v;
        __syncthreads();
    }
    int off0 = tsum[t] - run;
#pragma unroll
    for (int j = 0; j < PBS; ++j) bins[base_ + j] += off0;
    __syncthreads();

    // emit row data (before bins mutate as cursors)
    for (int l = t; l < SBN; l += PBT) {
        int v = (g << SBSH) + l;
        if (v < NNODES) {
            int b0 = bins[8 * l];
            int b1 = (l == SBN - 1) ? len : bins[8 * l + 8];
            row_beg[v] = rb + b0;
            row_end[v] = rb + b1;
            float di = rsqrtf((float)(b1 - b0) + 1.0f);
            dinv[v] = di;
            union { uint2 u; __half2 h[2]; } st;
            st.h[0] = __floats2half2_rn(di * x[3 * v + 0], di * x[3 * v + 1]);
            st.h[1] = __floats2half2_rn(di * x[3 * v + 2], 0.0f);
            *(uint2*)(y1h + 4 * (size_t)v) = st.u;
            // pack per-chunk start deltas (chunk 0 delta is 0)
            union { unsigned char b[8]; uint2 u; } pk;
            pk.b[0] = 0;
#pragma unroll
            for (int c = 1; c < 8; ++c) {
                int d = bins[8 * l + c] - b0;
                pk.b[c] = (unsigned char)(d > 255 ? 255 : d);
            }
            coff8[v] = pk.u;
        }
    }
    __syncthreads();

    // scatter to exact positions (writes stay in the 68 KB L2-resident window)
    for (int k = 4 * t; k < len4; k += 4 * PBT) {
        uint4 p4 = *(const uint4*)(staged + rb + k);
        unsigned pp[4] = {p4.x, p4.y, p4.z, p4.w};
#pragma unroll
        for (int u = 0; u < 4; ++u) {
            int pos = atomicAdd(&bins[BIN(pp[u])], 1);
            eidx[rb + pos] = pp[u] & 0x7FFFFu;
        }
    }
    for (int k = len4 + t; k < len; k += PBT) {
        unsigned p = staged[rb + k];
        int pos = atomicAdd(&bins[BIN(p)], 1);
        eidx[rb + pos] = p & 0x7FFFFu;
    }
}

// ---------------- layer 1: node-centric register accumulation + fused transform ----------------
// R11-exact: 1 node/thread, 500K threads (max TLP). R12 proved 2 nodes/thread
// (250K threads) loses ~19 us: on a latency-bound gather with free thread
// count, TLP beats ILP.
__global__ __launch_bounds__(256) void agg1t1_kernel(const unsigned int* __restrict__ eidx,
                                                     const int* __restrict__ row_beg,
                                                     const int* __restrict__ row_end,
                                                     const __half* __restrict__ y1h,
                                                     const float* __restrict__ dinv,
                                                     const float* __restrict__ W1,
                                                     const float* __restrict__ b1,
                                                     __half* __restrict__ y2h, int n) {
    int v = blockIdx.x * 256 + threadIdx.x;
    if (v >= n) return;
    int beg = row_beg[v], end = row_end[v];
    union { uint2 u2; __half2 h[2]; } sf;
    sf.u2 = *(const uint2*)(y1h + 4 * (size_t)v);
    float2 f01 = __half22float2(sf.h[0]);
    float2 f23 = __half22float2(sf.h[1]);
    float a0 = f01.x, a1 = f01.y, a2 = f23.x;
    int i = beg;
    for (; i + 3 < end; i += 4) {
        unsigned e0 = eidx[i], e1 = eidx[i + 1], e2 = eidx[i + 2], e3 = eidx[i + 3];
        uint2 w0 = *(const uint2*)(y1h + 4 * (size_t)e0);
        uint2 w1 = *(const uint2*)(y1h + 4 * (size_t)e1);
        uint2 w2 = *(const uint2*)(y1h + 4 * (size_t)e2);
        uint2 w3 = *(const uint2*)(y1h + 4 * (size_t)e3);
        uint2 ww[4] = {w0, w1, w2, w3};
#pragma unroll
        for (int u = 0; u < 4; ++u) {
            union { uint2 u2; __half2 h[2]; } g; g.u2 = ww[u];
            float2 p01 = __half22float2(g.h[0]);
            float2 p23 = __half22float2(g.h[1]);
            a0 += p01.x; a1 += p01.y; a2 += p23.x;
        }
    }
    for (; i < end; ++i) {
        unsigned e = eidx[i];
        union { uint2 u2; __half2 h[2]; } g;
        g.u2 = *(const uint2*)(y1h + 4 * (size_t)e);
        float2 p01 = __half22float2(g.h[0]);
        float2 p23 = __half22float2(g.h[1]);
        a0 += p01.x; a1 += p01.y; a2 += p23.x;
    }
    float di = dinv[v];
    a0 *= di; a1 *= di; a2 *= di;
    float hf[16];
#pragma unroll
    for (int j = 0; j < 16; ++j) {
        float h = b1[j] + a0 * W1[j] + a1 * W1[16 + j] + a2 * W1[32 + j];
        hf[j] = di * fmaxf(h, 0.0f);
    }
    union { uint4 u[2]; __half2 h[8]; } st;
#pragma unroll
    for (int q = 0; q < 8; ++q) st.h[q] = __floats2half2_rn(hf[2 * q], hf[2 * q + 1]);
    uint4* dp = (uint4*)(y2h + 16 * (size_t)v);
    dp[0] = st.u[0];
    dp[1] = st.u[1];
}

// ---------------- layer 2: chunk-synchronized node-centric aggregation ----------------
__device__ __forceinline__ void addh8(float* a, uint4 w) {
    union { uint4 u4; __half2 h[4]; } g; g.u4 = w;
#pragma unroll
    for (int q = 0; q < 4; ++q) {
        float2 f = __half22float2(g.h[q]);
        a[2 * q + 0] += f.x;
        a[2 * q + 1] += f.y;
    }
}

__device__ __forceinline__ int gather_seg(const unsigned int* __restrict__ eidx,
                                          const __half* __restrict__ y2h,
                                          int i, int lim, float* a) {
    for (; i + 3 < lim; i += 4) {
        unsigned e0 = eidx[i], e1 = eidx[i + 1], e2 = eidx[i + 2], e3 = eidx[i + 3];
        const uint4* p0 = (const uint4*)(y2h + 16 * (size_t)e0);
        const uint4* p1 = (const uint4*)(y2h + 16 * (size_t)e1);
        const uint4* p2 = (const uint4*)(y2h + 16 * (size_t)e2);
        const uint4* p3 = (const uint4*)(y2h + 16 * (size_t)e3);
        uint4 w0a = p0[0], w0b = p0[1];
        uint4 w1a = p1[0], w1b = p1[1];
        uint4 w2a = p2[0], w2b = p2[1];
        uint4 w3a = p3[0], w3b = p3[1];
        addh8(a, w0a); addh8(a + 8, w0b);
        addh8(a, w1a); addh8(a + 8, w1b);
        addh8(a, w2a); addh8(a + 8, w2b);
        addh8(a, w3a); addh8(a + 8, w3b);
    }
    for (; i < lim; ++i) {
        unsigned e = eidx[i];
        const uint4* p = (const uint4*)(y2h + 16 * (size_t)e);
        uint4 wa = p[0], wb = p[1];
        addh8(a, wa); addh8(a + 8, wb);
    }
    return i;
}

__device__ __forceinline__ void finish_node(const float* a, float di,
                                            const float* __restrict__ W2,
                                            const float* __restrict__ b2,
                                            float* __restrict__ out, int v) {
    float s16[16];
#pragma unroll
    for (int k = 0; k < 16; ++k) s16[k] = a[k] * di;
    float z[10];
#pragma unroll
    for (int j = 0; j < 10; ++j) {
        float s = b2[j];
#pragma unroll
        for (int k = 0; k < 16; ++k) s += s16[k] * W2[k * 10 + j];
        z[j] = s;
    }
    float m = z[0];
#pragma unroll
    for (int j = 1; j < 10; ++j) m = fmaxf(m, z[j]);
    float sum = 0.0f;
#pragma unroll
    for (int j = 0; j < 10; ++j) sum += expf(z[j] - m);
    float lse = logf(sum);
    float* ov = out + 10 * (size_t)v;
#pragma unroll
    for (int j = 0; j < 10; ++j) ov[j] = z[j] - m - lse;
}

// R3-exact configuration (measured 104 us / 282 MB fetch): one block per
// super-bucket; 512 threads x 2 rows SEQUENTIAL per phase; block barrier
// between the 8 src-chunk phases. Verified bistable-thrash evidence (R4-R8):
// any per-block speedup shortens the sweep, cross-block stagger then spans
// >L2-worth of windows -> fetch 282->370+ MB and NET SLOWDOWN. Grid coherence
// reaches the 213 MB floor but 489 same-word device atomics cost ~73 us/phase.
// DO NOT speed up the per-block inner loop without grid-level pacing.
__global__ __launch_bounds__(512, 4) void agg2t2_kernel(const unsigned int* __restrict__ eidx,
                                                        const int* __restrict__ row_beg,
                                                        const int* __restrict__ row_end,
                                                        const uint2* __restrict__ coff8,
                                                        const __half* __restrict__ y2h,
                                                        const float* __restrict__ dinv,
                                                        const float* __restrict__ W2,
                                                        const float* __restrict__ b2,
                                                        float* __restrict__ out) {
    const int g = blockIdx.x;
    const int t = threadIdx.x;
    const int v0 = (g << SBSH) + t;
    const int v1 = v0 + 512;
    const bool ok0 = v0 < NNODES;
    const bool ok1 = v1 < NNODES;

    float a0[16], a1[16];
#pragma unroll
    for (int k = 0; k < 16; ++k) { a0[k] = 0.0f; a1[k] = 0.0f; }

    int i0 = 0, end0 = 0, i1 = 0, end1 = 0;
    unsigned long long pk0 = 0ull, pk1 = 0ull;
    if (ok0) {
        const uint4* sp = (const uint4*)(y2h + 16 * (size_t)v0);
        uint4 s0 = sp[0], s1 = sp[1];
        addh8(a0, s0); addh8(a0 + 8, s1);
        i0 = row_beg[v0]; end0 = row_end[v0];
        uint2 c = coff8[v0];
        pk0 = ((unsigned long long)c.y << 32) | c.x;
    }
    if (ok1) {
        const uint4* sp = (const uint4*)(y2h + 16 * (size_t)v1);
        uint4 s0 = sp[0], s1 = sp[1];
        addh8(a1, s0); addh8(a1 + 8, s1);
        i1 = row_beg[v1]; end1 = row_end[v1];
        uint2 c = coff8[v1];
        pk1 = ((unsigned long long)c.y << 32) | c.x;
    }
    const int beg0 = i0, beg1 = i1;

    for (int c = 1; c <= 8; ++c) {
        int sh = (8 * c) & 63;
        int lim0 = (c == 8) ? end0 : beg0 + (int)((pk0 >> sh) & 255ull);
        int lim1 = (c == 8) ? end1 : beg1 + (int)((pk1 >> sh) & 255ull);
        i0 = gather_seg(eidx, y2h, i0, lim0, a0);
        i1 = gather_seg(eidx, y2h, i1, lim1, a1);
        if (c < 8) __syncthreads();
    }

    if (ok0) finish_node(a0, dinv[v0], W2, b2, out, v0);
    if (ok1) finish_node(a1, dinv[v1], W2, b2, out, v1);
}

extern "C" void kernel_launch(void* const* d_in, const int* in_sizes, int n_in,
                              void* d_out, int out_size, void* d_ws, size_t ws_size,
                              hipStream_t stream) {
    const float* x  = (const float*)d_in[0];
    const int*   ei = (const int*)d_in[1];
    const float* W1 = (const float*)d_in[2];
    const float* b1 = (const float*)d_in[3];
    const float* W2 = (const float*)d_in[4];
    const float* b2 = (const float*)d_in[5];
    float* out = (float*)d_out;

    const int E = in_sizes[1] / 2;            // 8,000,000
    const int* src = ei;
    const int* dst = ei + E;

    // workspace layout (words)
    int*          ws_i    = (int*)d_ws;
    int*          gcursor = ws_i;                                   // 512
    int*          row_beg = ws_i + 512;                             // N
    int*          row_end = ws_i + 512 + 500000;                    // N
    float*        dinv    = (float*)(ws_i + 512 + 1000000);         // N
    __half*       y1h     = (__half*)(ws_i + 512 + 1500000);        // 4N halves (1M words)
    unsigned int* staged  = (unsigned int*)(ws_i + 512 + 2500000);  // 512*CAP = 8,716,288
    unsigned int* eidx    = staged + (size_t)NSB * CAP;             // 8,716,288
    uint2*        coff8   = (uint2*)(eidx + (size_t)NSB * CAP);     // 524288 * 8 B = 1,048,576 words
    __half*       y2h     = (__half*)staged;                        // overlay: staged dead after passB
    // total ~ 20.98M words = 83.9 MB

    hipMemsetAsync(gcursor, 0, NSB * sizeof(int), stream);

    int nblk = (E + CHUNK - 1) / CHUNK;       // 977
    scatter_kernel<<<nblk, SCT, 0, stream>>>(src, dst, gcursor, staged, E);
    passB_kernel<<<NSB, PBT, 0, stream>>>(staged, gcursor, eidx, row_beg, row_end, dinv, x, y1h, coff8);
    agg1t1_kernel<<<NAGG, 256, 0, stream>>>(eidx, row_beg, row_end, y1h, dinv, W1, b1, y2h, NNODES);
    agg2t2_kernel<<<NSB, 512, 0, stream>>>(eidx, row_beg, row_end, coff8, y2h, dinv, W2, b2, out);
}

// Round 16
// 357.316 us; speedup vs baseline: 1.1247x; 1.0090x over previous
//
#include <hip/hip_runtime.h>
#include <hip/hip_fp16.h>

#define NNODES    500000
#define SBSH      10            // super-bucket = dst >> 10
#define NSB       512           // super-bucket count (covers 524288 >= N)
#define SBN       1024          // nodes per super-bucket
#define CAP       17024         // staged region words (mean 15625, +11 sigma), mult of 16
#define CHUNK     8192          // edges per scatter block
#define SCT       512           // scatter threads per block
#define NAGG      1954          // ceil(N/256) — agg1 grid, 1 node/thread (max TLP; R12 proved 2/thread loses)
#define NBIN      8192          // passB bins: dst_low10 * 8 + src_high3
#define PBT       1024          // passB threads per block
#define PBS       (NBIN / PBT)  // scan bins per thread (8)

// bin key: group rows by dst, order within row by src-chunk (2 MB y2h windows)
#define BIN(p) ((int)(((p) >> 19) * 8u + (((p) & 0x7FFFFu) >> 16)))

// ---------------- pass 1: coarse scatter, single-read + LDS counting-sort ----------------
// R15 verified CHUNK=8192@512thr at ~48 us. Now SINGLE global read: each
// thread holds its 4 (dst,src) uint4 pairs in registers (full compile-time
// unroll -> no scratch) across histogram + scan, then sorts from registers.
// Removes the entire pass-2 re-read (issue slots + addr calc + L2 traffic).
__global__ __launch_bounds__(SCT) void scatter_kernel(const int* __restrict__ src,
                                                      const int* __restrict__ dst,
                                                      int* __restrict__ gcursor,
                                                      unsigned int* __restrict__ staged, int E) {
    __shared__ int cnt[NSB];                 // histogram -> start[] after scan
    __shared__ int addb[NSB];                // global seg base -> addbase = gbase - start
    __shared__ int lcur[NSB];                // LDS sort cursors
    __shared__ int tsum[SCT];
    __shared__ unsigned int sorted[CHUNK];   // 32 KB payloads, bucket-ordered
    __shared__ unsigned short sbuck[CHUNK];  // 16 KB bucket id per slot

    const int t = threadIdx.x;
    cnt[t] = 0;                              // SCT == NSB: one bucket per thread
    __syncthreads();

    const int lo = blockIdx.x * CHUNK;
    const int hi = min(E, lo + CHUNK);
    const int len = hi - lo;
    const int len4 = lo + (len & ~3);
    const int base_i = lo + 4 * t;

    // single load pass: 4 register-resident uint4 pairs + histogram
    uint4 rd[4], rs[4];
#pragma unroll
    for (int j = 0; j < 4; ++j) {
        int i = base_i + j * 4 * SCT;
        if (i < len4) {
            rd[j] = *(const uint4*)(dst + i);
            rs[j] = *(const uint4*)(src + i);
            atomicAdd(&cnt[rd[j].x >> SBSH], 1);
            atomicAdd(&cnt[rd[j].y >> SBSH], 1);
            atomicAdd(&cnt[rd[j].z >> SBSH], 1);
            atomicAdd(&cnt[rd[j].w >> SBSH], 1);
        }
    }
    for (int i = len4 + t; i < hi; i += SCT)
        atomicAdd(&cnt[((unsigned)dst[i]) >> SBSH], 1);
    __syncthreads();

    // reserve global segment for this block's share of each bucket
    int c0 = cnt[t];
    addb[t] = c0 ? atomicAdd(&gcursor[t], c0) : 0;

    // exclusive scan of 512 counts (1 per thread + block scan)
    tsum[t] = c0;
    __syncthreads();
    for (int off = 1; off < SCT; off <<= 1) {
        int v = (t >= off) ? tsum[t - off] : 0;
        __syncthreads();
        tsum[t] += v;
        __syncthreads();
    }
    int st0 = tsum[t] - c0;                  // exclusive start of bucket t
    cnt[t] = st0;                            // cnt[] now = start[]
    lcur[t] = st0;
    addb[t] -= st0;                          // addbase = gbase - start
    __syncthreads();

    // sort pass from registers (no global re-read)
#pragma unroll
    for (int j = 0; j < 4; ++j) {
        int i = base_i + j * 4 * SCT;
        if (i < len4) {
            unsigned dd[4] = {rd[j].x, rd[j].y, rd[j].z, rd[j].w};
            unsigned ss[4] = {rs[j].x, rs[j].y, rs[j].z, rs[j].w};
#pragma unroll
            for (int u = 0; u < 4; ++u) {
                unsigned b = dd[u] >> SBSH;
                int pos = atomicAdd(&lcur[b], 1);
                sorted[pos] = ((dd[u] & (SBN - 1u)) << 19) | ss[u];
                sbuck[pos] = (unsigned short)b;
            }
        }
    }
    for (int i = len4 + t; i < hi; i += SCT) {   // tail (last block only): reload
        unsigned d = (unsigned)dst[i], s = (unsigned)src[i];
        unsigned b = d >> SBSH;
        int pos = atomicAdd(&lcur[b], 1);
        sorted[pos] = ((d & (SBN - 1u)) << 19) | s;
        sbuck[pos] = (unsigned short)b;
    }
    __syncthreads();

    // coalesced flush — consecutive i within a bucket hit consecutive global
    // addresses; runs average ~16 words -> full-line stores.
    for (int i = t; i < len; i += SCT) {
        unsigned p = sorted[i];
        int b = sbuck[i];
        staged[(size_t)b * CAP + addb[b] + i] = p;
    }
}

// ---------------- passB: per-super-bucket CSR, rows src-chunk-ordered ----------------
__global__ __launch_bounds__(PBT) void passB_kernel(const unsigned int* __restrict__ staged,
                                                    const int* __restrict__ gcnt,
                                                    unsigned int* __restrict__ eidx,
                                                    int* __restrict__ row_beg,
                                                    int* __restrict__ row_end,
                                                    float* __restrict__ dinv,
                                                    const float* __restrict__ x,
                                                    __half* __restrict__ y1h,
                                                    uint2* __restrict__ coff8) {
    __shared__ int bins[NBIN];                // 32 KB
    __shared__ int tsum[PBT];                 // 4 KB
    const int t = threadIdx.x;
    const int g = blockIdx.x;
    const int len = gcnt[g];
    const int rb = g * CAP;

    for (int i = t; i < NBIN; i += PBT) bins[i] = 0;
    __syncthreads();

    // histogram over 8192 (dst_low, src_chunk) bins
    int len4 = len & ~3;
    for (int k = 4 * t; k < len4; k += 4 * PBT) {
        uint4 p4 = *(const uint4*)(staged + rb + k);
        atomicAdd(&bins[BIN(p4.x)], 1);
        atomicAdd(&bins[BIN(p4.y)], 1);
        atomicAdd(&bins[BIN(p4.z)], 1);
        atomicAdd(&bins[BIN(p4.w)], 1);
    }
    for (int k = len4 + t; k < len; k += PBT) atomicAdd(&bins[BIN(staged[rb + k])], 1);
    __syncthreads();

    // in-place exclusive scan of 8192 bins (PBS per thread + block scan)
    int base_ = PBS * t;
    int run = 0;
#pragma unroll
    for (int j = 0; j < PBS; ++j) {
        int c = bins[base_ + j];
        bins[base_ + j] = run;
        run += c;
    }
    tsum[t] = run;
    __syncthreads();
    for (int off = 1; off < PBT; off <<= 1) {
        int v = (t >= off) ? tsum[t - off] : 0;
        __syncthreads();
        tsum[t] += v;
        __syncthreads();
    }
    int off0 = tsum[t] - run;
#pragma unroll
    for (int j = 0; j < PBS; ++j) bins[base_ + j] += off0;
    __syncthreads();

    // emit row data (before bins mutate as cursors)
    for (int l = t; l < SBN; l += PBT) {
        int v = (g << SBSH) + l;
        if (v < NNODES) {
            int b0 = bins[8 * l];
            int b1 = (l == SBN - 1) ? len : bins[8 * l + 8];
            row_beg[v] = rb + b0;
            row_end[v] = rb + b1;
            float di = rsqrtf((float)(b1 - b0) + 1.0f);
            dinv[v] = di;
            union { uint2 u; __half2 h[2]; } st;
            st.h[0] = __floats2half2_rn(di * x[3 * v + 0], di * x[3 * v + 1]);
            st.h[1] = __floats2half2_rn(di * x[3 * v + 2], 0.0f);
            *(uint2*)(y1h + 4 * (size_t)v) = st.u;
            // pack per-chunk start deltas (chunk 0 delta is 0)
            union { unsigned char b[8]; uint2 u; } pk;
            pk.b[0] = 0;
#pragma unroll
            for (int c = 1; c < 8; ++c) {
                int d = bins[8 * l + c] - b0;
                pk.b[c] = (unsigned char)(d > 255 ? 255 : d);
            }
            coff8[v] = pk.u;
        }
    }
    __syncthreads();

    // scatter to exact positions (writes stay in the 68 KB L2-resident window)
    for (int k = 4 * t; k < len4; k += 4 * PBT) {
        uint4 p4 = *(const uint4*)(staged + rb + k);
        unsigned pp[4] = {p4.x, p4.y, p4.z, p4.w};
#pragma unroll
        for (int u = 0; u < 4; ++u) {
            int pos = atomicAdd(&bins[BIN(pp[u])], 1);
            eidx[rb + pos] = pp[u] & 0x7FFFFu;
        }
    }
    for (int k = len4 + t; k < len; k += PBT) {
        unsigned p = staged[rb + k];
        int pos = atomicAdd(&bins[BIN(p)], 1);
        eidx[rb + pos] = p & 0x7FFFFu;
    }
}

// ---------------- layer 1: node-centric register accumulation + fused transform ----------------
// R11-exact: 1 node/thread, 500K threads (max TLP). R12 proved 2 nodes/thread
// (250K threads) loses ~19 us: on a latency-bound gather with free thread
// count, TLP beats ILP.
__global__ __launch_bounds__(256) void agg1t1_kernel(const unsigned int* __restrict__ eidx,
                                                     const int* __restrict__ row_beg,
                                                     const int* __restrict__ row_end,
                                                     const __half* __restrict__ y1h,
                                                     const float* __restrict__ dinv,
                                                     const float* __restrict__ W1,
                                                     const float* __restrict__ b1,
                                                     __half* __restrict__ y2h, int n) {
    int v = blockIdx.x * 256 + threadIdx.x;
    if (v >= n) return;
    int beg = row_beg[v], end = row_end[v];
    union { uint2 u2; __half2 h[2]; } sf;
    sf.u2 = *(const uint2*)(y1h + 4 * (size_t)v);
    float2 f01 = __half22float2(sf.h[0]);
    float2 f23 = __half22float2(sf.h[1]);
    float a0 = f01.x, a1 = f01.y, a2 = f23.x;
    int i = beg;
    for (; i + 3 < end; i += 4) {
        unsigned e0 = eidx[i], e1 = eidx[i + 1], e2 = eidx[i + 2], e3 = eidx[i + 3];
        uint2 w0 = *(const uint2*)(y1h + 4 * (size_t)e0);
        uint2 w1 = *(const uint2*)(y1h + 4 * (size_t)e1);
        uint2 w2 = *(const uint2*)(y1h + 4 * (size_t)e2);
        uint2 w3 = *(const uint2*)(y1h + 4 * (size_t)e3);
        uint2 ww[4] = {w0, w1, w2, w3};
#pragma unroll
        for (int u = 0; u < 4; ++u) {
            union { uint2 u2; __half2 h[2]; } g; g.u2 = ww[u];
            float2 p01 = __half22float2(g.h[0]);
            float2 p23 = __half22float2(g.h[1]);
            a0 += p01.x; a1 += p01.y; a2 += p23.x;
        }
    }
    for (; i < end; ++i) {
        unsigned e = eidx[i];
        union { uint2 u2; __half2 h[2]; } g;
        g.u2 = *(const uint2*)(y1h + 4 * (size_t)e);
        float2 p01 = __half22float2(g.h[0]);
        float2 p23 = __half22float2(g.h[1]);
        a0 += p01.x; a1 += p01.y; a2 += p23.x;
    }
    float di = dinv[v];
    a0 *= di; a1 *= di; a2 *= di;
    float hf[16];
#pragma unroll
    for (int j = 0; j < 16; ++j) {
        float h = b1[j] + a0 * W1[j] + a1 * W1[16 + j] + a2 * W1[32 + j];
        hf[j] = di * fmaxf(h, 0.0f);
    }
    union { uint4 u[2]; __half2 h[8]; } st;
#pragma unroll
    for (int q = 0; q < 8; ++q) st.h[q] = __floats2half2_rn(hf[2 * q], hf[2 * q + 1]);
    uint4* dp = (uint4*)(y2h + 16 * (size_t)v);
    dp[0] = st.u[0];
    dp[1] = st.u[1];
}

// ---------------- layer 2: chunk-synchronized node-centric aggregation ----------------
__device__ __forceinline__ void addh8(float* a, uint4 w) {
    union { uint4 u4; __half2 h[4]; } g; g.u4 = w;
#pragma unroll
    for (int q = 0; q < 4; ++q) {
        float2 f = __half22float2(g.h[q]);
        a[2 * q + 0] += f.x;
        a[2 * q + 1] += f.y;
    }
}

__device__ __forceinline__ int gather_seg(const unsigned int* __restrict__ eidx,
                                          const __half* __restrict__ y2h,
                                          int i, int lim, float* a) {
    for (; i + 3 < lim; i += 4) {
        unsigned e0 = eidx[i], e1 = eidx[i + 1], e2 = eidx[i + 2], e3 = eidx[i + 3];
        const uint4* p0 = (const uint4*)(y2h + 16 * (size_t)e0);
        const uint4* p1 = (const uint4*)(y2h + 16 * (size_t)e1);
        const uint4* p2 = (const uint4*)(y2h + 16 * (size_t)e2);
        const uint4* p3 = (const uint4*)(y2h + 16 * (size_t)e3);
        uint4 w0a = p0[0], w0b = p0[1];
        uint4 w1a = p1[0], w1b = p1[1];
        uint4 w2a = p2[0], w2b = p2[1];
        uint4 w3a = p3[0], w3b = p3[1];
        addh8(a, w0a); addh8(a + 8, w0b);
        addh8(a, w1a); addh8(a + 8, w1b);
        addh8(a, w2a); addh8(a + 8, w2b);
        addh8(a, w3a); addh8(a + 8, w3b);
    }
    for (; i < lim; ++i) {
        unsigned e = eidx[i];
        const uint4* p = (const uint4*)(y2h + 16 * (size_t)e);
        uint4 wa = p[0], wb = p[1];
        addh8(a, wa); addh8(a + 8, wb);
    }
    return i;
}

__device__ __forceinline__ void finish_node(const float* a, float di,
                                            const float* __restrict__ W2,
                                            const float* __restrict__ b2,
                                            float* __restrict__ out, int v) {
    float s16[16];
#pragma unroll
    for (int k = 0; k < 16; ++k) s16[k] = a[k] * di;
    float z[10];
#pragma unroll
    for (int j = 0; j < 10; ++j) {
        float s = b2[j];
#pragma unroll
        for (int k = 0; k < 16; ++k) s += s16[k] * W2[k * 10 + j];
        z[j] = s;
    }
    float m = z[0];
#pragma unroll
    for (int j = 1; j < 10; ++j) m = fmaxf(m, z[j]);
    float sum = 0.0f;
#pragma unroll
    for (int j = 0; j < 10; ++j) sum += expf(z[j] - m);
    float lse = logf(sum);
    float* ov = out + 10 * (size_t)v;
#pragma unroll
    for (int j = 0; j < 10; ++j) ov[j] = z[j] - m - lse;
}

// R3-exact configuration (measured 104 us / 282 MB fetch): one block per
// super-bucket; 512 threads x 2 rows SEQUENTIAL per phase; block barrier
// between the 8 src-chunk phases. Verified bistable-thrash evidence (R4-R8):
// any per-block speedup shortens the sweep, cross-block stagger then spans
// >L2-worth of windows -> fetch 282->370+ MB and NET SLOWDOWN. Grid coherence
// reaches the 213 MB floor but 489 same-word device atomics cost ~73 us/phase.
// DO NOT speed up the per-block inner loop without grid-level pacing.
__global__ __launch_bounds__(512, 4) void agg2t2_kernel(const unsigned int* __restrict__ eidx,
                                                        const int* __restrict__ row_beg,
                                                        const int* __restrict__ row_end,
                                                        const uint2* __restrict__ coff8,
                                                        const __half* __restrict__ y2h,
                                                        const float* __restrict__ dinv,
                                                        const float* __restrict__ W2,
                                                        const float* __restrict__ b2,
                                                        float* __restrict__ out) {
    const int g = blockIdx.x;
    const int t = threadIdx.x;
    const int v0 = (g << SBSH) + t;
    const int v1 = v0 + 512;
    const bool ok0 = v0 < NNODES;
    const bool ok1 = v1 < NNODES;

    float a0[16], a1[16];
#pragma unroll
    for (int k = 0; k < 16; ++k) { a0[k] = 0.0f; a1[k] = 0.0f; }

    int i0 = 0, end0 = 0, i1 = 0, end1 = 0;
    unsigned long long pk0 = 0ull, pk1 = 0ull;
    if (ok0) {
        const uint4* sp = (const uint4*)(y2h + 16 * (size_t)v0);
        uint4 s0 = sp[0], s1 = sp[1];
        addh8(a0, s0); addh8(a0 + 8, s1);
        i0 = row_beg[v0]; end0 = row_end[v0];
        uint2 c = coff8[v0];
        pk0 = ((unsigned long long)c.y << 32) | c.x;
    }
    if (ok1) {
        const uint4* sp = (const uint4*)(y2h + 16 * (size_t)v1);
        uint4 s0 = sp[0], s1 = sp[1];
        addh8(a1, s0); addh8(a1 + 8, s1);
        i1 = row_beg[v1]; end1 = row_end[v1];
        uint2 c = coff8[v1];
        pk1 = ((unsigned long long)c.y << 32) | c.x;
    }
    const int beg0 = i0, beg1 = i1;

    for (int c = 1; c <= 8; ++c) {
        int sh = (8 * c) & 63;
        int lim0 = (c == 8) ? end0 : beg0 + (int)((pk0 >> sh) & 255ull);
        int lim1 = (c == 8) ? end1 : beg1 + (int)((pk1 >> sh) & 255ull);
        i0 = gather_seg(eidx, y2h, i0, lim0, a0);
        i1 = gather_seg(eidx, y2h, i1, lim1, a1);
        if (c < 8) __syncthreads();
    }

    if (ok0) finish_node(a0, dinv[v0], W2, b2, out, v0);
    if (ok1) finish_node(a1, dinv[v1], W2, b2, out, v1);
}

extern "C" void kernel_launch(void* const* d_in, const int* in_sizes, int n_in,
                              void* d_out, int out_size, void* d_ws, size_t ws_size,
                              hipStream_t stream) {
    const float* x  = (const float*)d_in[0];
    const int*   ei = (const int*)d_in[1];
    const float* W1 = (const float*)d_in[2];
    const float* b1 = (const float*)d_in[3];
    const float* W2 = (const float*)d_in[4];
    const float* b2 = (const float*)d_in[5];
    float* out = (float*)d_out;

    const int E = in_sizes[1] / 2;            // 8,000,000
    const int* src = ei;
    const int* dst = ei + E;

    // workspace layout (words)
    int*          ws_i    = (int*)d_ws;
    int*          gcursor = ws_i;                                   // 512
    int*          row_beg = ws_i + 512;                             // N
    int*          row_end = ws_i + 512 + 500000;                    // N
    float*        dinv    = (float*)(ws_i + 512 + 1000000);         // N
    __half*       y1h     = (__half*)(ws_i + 512 + 1500000);        // 4N halves (1M words)
    unsigned int* staged  = (unsigned int*)(ws_i + 512 + 2500000);  // 512*CAP = 8,716,288
    unsigned int* eidx    = staged + (size_t)NSB * CAP;             // 8,716,288
    uint2*        coff8   = (uint2*)(eidx + (size_t)NSB * CAP);     // 524288 * 8 B = 1,048,576 words
    __half*       y2h     = (__half*)staged;                        // overlay: staged dead after passB
    // total ~ 20.98M words = 83.9 MB

    hipMemsetAsync(gcursor, 0, NSB * sizeof(int), stream);

    int nblk = (E + CHUNK - 1) / CHUNK;       // 977
    scatter_kernel<<<nblk, SCT, 0, stream>>>(src, dst, gcursor, staged, E);
    passB_kernel<<<NSB, PBT, 0, stream>>>(staged, gcursor, eidx, row_beg, row_end, dinv, x, y1h, coff8);
    agg1t1_kernel<<<NAGG, 256, 0, stream>>>(eidx, row_beg, row_end, y1h, dinv, W1, b1, y2h, NNODES);
    agg2t2_kernel<<<NSB, 512, 0, stream>>>(eidx, row_beg, row_end, coff8, y2h, dinv, W2, b2, out);
}